// Round 10
// baseline (127.007 us; speedup 1.0000x reference)
//
#include <hip/hip_runtime.h>

// ---------------- problem constants (fixed by reference) ----------------
#define T_DIM 110
#define B_DIM 256
#define D_DIM 512
#define H_DIM 512
#define K_CAT 1024              // K layout: interleaved (fr0,fi0,fr1,fi1,...)
#define M_DIM (T_DIM * B_DIM)   // 28160
#define BD    (B_DIM * D_DIM)   // 131072
#define EPSV 1e-9f

typedef float f32x4 __attribute__((ext_vector_type(4)));
typedef short bf16x8 __attribute__((ext_vector_type(8)));

static __device__ __forceinline__ unsigned short f2bf(float f) {
    unsigned u = __builtin_bit_cast(unsigned, f);
    u += 0x7fffu + ((u >> 16) & 1u);      // round-to-nearest-even
    return (unsigned short)(u >> 16);
}

// ---------------- kernel 1: weight prep, INTERLEAVED columns ------------------
// Bt[h][2j] = (W1+W2)[h][j] (multiplies fr_j); Bt[h][2j+1] = (W1-W2)[h][j]
// (multiplies fi_j). bias = 2*b1 (b2 cancels in xr+xi).
__global__ __launch_bounds__(256) void prep_w_kernel(
    const float* __restrict__ W1, const float* __restrict__ b1,
    const float* __restrict__ W2,
    unsigned short* __restrict__ Bt,   // [H][K_CAT] bf16
    float* __restrict__ bias2)         // [H]
{
    int i = blockIdx.x * 256 + threadIdx.x;
    if (i < H_DIM) bias2[i] = 2.0f * b1[i];
    if (i >= H_DIM * K_CAT) return;
    int h = i / K_CAT;
    int k = i % K_CAT;
    int j = k >> 1;
    float w = (k & 1) ? (W1[h * D_DIM + j] - W2[h * D_DIM + j])
                      : (W1[h * D_DIM + j] + W2[h * D_DIM + j]);
    Bt[i] = f2bf(w);
}

// ---------------- kernel 1b: turn-phase sincos table TT[t][d] = (ca,sa,cb,sb) --
__global__ __launch_bounds__(256) void prep_tt_kernel(
    const float* __restrict__ turna, const float* __restrict__ turnb,
    float4* __restrict__ TT)
{
    int i = blockIdx.x * 256 + threadIdx.x;
    if (i >= T_DIM * D_DIM) return;
    float s1, c1, s2, c2;
    __sincosf(turna[i], &s1, &c1);
    __sincosf(turnb[i], &s2, &c2);
    TT[i] = make_float4(c1, s1, c2, s2);
}

// ---------------- kernel 2: fused features + scan -> A[M][K_CAT] bf16 ----------
// Thread = one (b,d). Slot-static register ring depth 4, unroll 4: slot
// (t+4)&3 == t&3, so each iteration consumes its named set then reloads the
// SAME variables for t+4 (no rotation copies -> no register churn; plain C
// loads -> compiler-managed waits, no vmcnt-count fragility).
// sched_barrier(0x387) = block ONLY VMEM from crossing iteration boundaries:
// pins prefetch loads at issue (R2 sinking fix) while letting VALU/DS flow
// across iterations (R6/R9 full-fence serialization fix).
// Serial tail shortened: rsq(max(m2,1e-30)) replaces the IEEE divide; the
// clamp keeps turn==0 exact (0 * finite = 0), matches ref to ~1e-7.
__global__ __launch_bounds__(256) void feat_scan_kernel(
    const float* __restrict__ a, const float* __restrict__ v,
    const float* __restrict__ l, const float* __restrict__ qmask,
    const float* __restrict__ mu_a, const float* __restrict__ mu_v,
    const float* __restrict__ mu_l,
    const float* __restrict__ shifta, const float* __restrict__ shiftv,
    const float4* __restrict__ TT,
    unsigned int* __restrict__ A32)    // [M][K_CAT/2] dwords (fr|fi<<16)
{
    __shared__ float qm_s[T_DIM], mua_s[T_DIM], muv_s[T_DIM], mul_s[T_DIM];
    const int tx = threadIdx.x;
    const int b  = blockIdx.x >> 1;
    const int d  = ((blockIdx.x & 1) << 8) + tx;
    if (tx < T_DIM) {
        qm_s[tx]  = qmask[(size_t)(tx * B_DIM + b) * 2];
        mua_s[tx] = mu_a[tx];
        muv_s[tx] = mu_v[tx];
        mul_s[tx] = mu_l[tx];
    }
    const float sa = shifta[d];
    const float sv = shiftv[d];
    __syncthreads();

    const size_t gbase = (size_t)b * D_DIM + d;

    // ---- prologue: fill the 4 slots (t = 0..3) ----
    float  s0a = a[gbase],                 s0v = v[gbase],
           s0l = l[gbase];
    float4 s0t = TT[d];
    float  s1a = a[(size_t)1 * BD + gbase], s1v = v[(size_t)1 * BD + gbase],
           s1l = l[(size_t)1 * BD + gbase];
    float4 s1t = TT[1 * D_DIM + d];
    float  s2a = a[(size_t)2 * BD + gbase], s2v = v[(size_t)2 * BD + gbase],
           s2l = l[(size_t)2 * BD + gbase];
    float4 s2t = TT[2 * D_DIM + d];
    float  s3a = a[(size_t)3 * BD + gbase], s3v = v[(size_t)3 * BD + gbase],
           s3l = l[(size_t)3 * BD + gbase];
    float4 s3t = TT[3 * D_DIM + d];

    // pre-init (1,1): with gate=0 at t=0 the generic select reproduces the
    // reference's t=0 rule exactly.
    float pAr = 1.f, pAi = 1.f, pBr = 1.f, pBi = 1.f;

#define ITER(tt_, SA_, SV_, SL_, ST_)                                          \
    {                                                                          \
        const int t_ = (tt_);                                                  \
        const float qa = qm_s[t_], ma = mua_s[t_],                             \
                    mv = muv_s[t_], ml = mul_s[t_];                            \
        float sA, cA, sV, cV, sL, cL;                                          \
        __sincosf(SA_ + sa, &sA, &cA);                                         \
        __sincosf(SV_ + sv, &sV, &cV);                                         \
        __sincosf(SL_,      &sL, &cL);                                         \
        float fr = ml * cL + ma * cA + mv * cV;                                \
        float fi = ml * sL + ma * sA + mv * sV;                                \
        const bool isA = qa > 0.5f;                                            \
        const float cp = isA ? ST_.x : ST_.z;                                  \
        const float sp = isA ? ST_.y : ST_.w;                                  \
        const float pr = isA ? pAr : pBr;                                      \
        const float pi = isA ? pAi : pBi;                                      \
        const float tr = pr * cp - pi * sp;                                    \
        const float ti = pr * sp + pi * cp;                                    \
        const float gate = (t_ == 0) ? 0.0f : 1.0f;                            \
        const float m2 = fmaxf(tr * tr + ti * ti, 1e-30f);                     \
        const float inv = gate * __builtin_amdgcn_rsqf(m2);                    \
        fr += tr * inv;                                                        \
        fi += ti * inv;                                                        \
        pAr = isA ? fr : pAr;  pAi = isA ? fi : pAi;                           \
        pBr = isA ? pBr : fr;  pBi = isA ? pBi : fi;                           \
        A32[(size_t)(t_ * B_DIM + b) * (K_CAT / 2) + d] =                      \
            (unsigned)f2bf(fr) | ((unsigned)f2bf(fi) << 16);                   \
        /* reload SAME slot for t+4 (clamped; tail dups harmless) */           \
        const int tnx = (t_ + 4 < T_DIM) ? t_ + 4 : T_DIM - 1;                 \
        SA_ = a[(size_t)tnx * BD + gbase];                                     \
        SV_ = v[(size_t)tnx * BD + gbase];                                     \
        SL_ = l[(size_t)tnx * BD + gbase];                                     \
        ST_ = TT[(size_t)tnx * D_DIM + d];                                     \
        /* directional fence: VMEM may not cross; VALU/SALU/DS may */          \
        __builtin_amdgcn_sched_barrier(0x387);                                 \
    }

    // 27 groups cover t = 0..107; peel 108 (slot0), 109 (slot1).
    for (int tb = 0; tb < 108; tb += 4) {
        ITER(tb,     s0a, s0v, s0l, s0t)
        ITER(tb + 1, s1a, s1v, s1l, s1t)
        ITER(tb + 2, s2a, s2v, s2l, s2t)
        ITER(tb + 3, s3a, s3v, s3l, s3t)
    }
    ITER(108, s0a, s0v, s0l, s0t)
    ITER(109, s1a, s1v, s1l, s1t)
#undef ITER
}

// ---------------- kernel 3: bf16 MFMA GEMM  C = A @ Bt^T + bias ---------------
// m97 structure + T3-minimum 2-phase double buffer: stage tile t+1 (via
// global_load_lds) BEFORE computing tile t; ONE __syncthreads per K-step
// (its implicit vmcnt/lgkm drain makes buf[t+1] ready and closes the reads
// of buf[t]). 128x128 tile, BK=64, 4 waves (2x2), 4x4 frags of 16x16x32.
#define BM 128
#define BN 128
#define BK 64
#define NT (K_CAT / BK)   // 16

__global__ __launch_bounds__(256) void gemm_kernel(
    const unsigned short* __restrict__ A,
    const unsigned short* __restrict__ Bt,
    const float* __restrict__ bias2,
    float* __restrict__ C)
{
    __shared__ __align__(16) unsigned short As[2][BM * BK];   // 2 x 16 KB
    __shared__ __align__(16) unsigned short Bs[2][BN * BK];   // 2 x 16 KB

    const int tid = threadIdx.x;
    const int wave = tid >> 6;
    const int lane = tid & 63;
    const int wr = wave >> 1;          // 0..1 (M dir)
    const int wc = wave & 1;           // 0..1 (N dir)
    const int m0 = blockIdx.x * BM;
    const int n0 = blockIdx.y * BN;
    const int lrow = lane & 15;
    const int lk8 = (lane >> 4) * 8;   // k-offset of this lane's 8 elements

    const int srow = wave * 32;        // first row this wave stages
    const int lrow8 = lane >> 3;       // row within 8-row group
    const int lchunk = lane & 7;       // 16B chunk within row

#define STAGE(buf_, k0_)                                                       \
    {                                                                          \
        const int kk0 = (k0_);                                                 \
        _Pragma("unroll")                                                      \
        for (int c = 0; c < 4; ++c) {                                          \
            const int row = srow + c * 8 + lrow8;                              \
            const unsigned short* gpA =                                        \
                A + (size_t)(m0 + row) * K_CAT + kk0 + lchunk * 8;             \
            unsigned short* lpA = &As[buf_][(srow + c * 8) * BK + lane * 8];   \
            __builtin_amdgcn_global_load_lds(                                  \
                (const __attribute__((address_space(1))) unsigned int*)gpA,    \
                (__attribute__((address_space(3))) unsigned int*)lpA,          \
                16, 0, 0);                                                     \
            const unsigned short* gpB =                                        \
                Bt + (size_t)(n0 + row) * K_CAT + kk0 + lchunk * 8;            \
            unsigned short* lpB = &Bs[buf_][(srow + c * 8) * BK + lane * 8];   \
            __builtin_amdgcn_global_load_lds(                                  \
                (const __attribute__((address_space(1))) unsigned int*)gpB,    \
                (__attribute__((address_space(3))) unsigned int*)lpB,          \
                16, 0, 0);                                                     \
        }                                                                      \
    }

    f32x4 acc[4][4] = {};

    STAGE(0, 0);
    __syncthreads();                       // buf0 ready

    for (int t = 0; t < NT; ++t) {
        const int cur = t & 1;
        if (t + 1 < NT) STAGE(cur ^ 1, (t + 1) * BK);   // overlap with compute

        bf16x8 af[4][2], bfv[4][2];
        #pragma unroll
        for (int m = 0; m < 4; ++m)
            #pragma unroll
            for (int kk = 0; kk < 2; ++kk)
                af[m][kk] = *reinterpret_cast<const bf16x8*>(
                    &As[cur][(wr * 64 + m * 16 + lrow) * BK + kk * 32 + lk8]);
        #pragma unroll
        for (int n = 0; n < 4; ++n)
            #pragma unroll
            for (int kk = 0; kk < 2; ++kk)
                bfv[n][kk] = *reinterpret_cast<const bf16x8*>(
                    &Bs[cur][(wc * 64 + n * 16 + lrow) * BK + kk * 32 + lk8]);

        #pragma unroll
        for (int kk = 0; kk < 2; ++kk)
            #pragma unroll
            for (int m = 0; m < 4; ++m)
                #pragma unroll
                for (int n = 0; n < 4; ++n)
                    acc[m][n] = __builtin_amdgcn_mfma_f32_16x16x32_bf16(
                        af[m][kk], bfv[n][kk], acc[m][n], 0, 0, 0);

        __syncthreads();   // drains staged loads; next buf ready, reads closed
    }
#undef STAGE

    // -------- epilogue: C/D layout col=lane&15, row=(lane>>4)*4+r  (m89/m91)
    const int rbase = m0 + wr * 64 + (lane >> 4) * 4;
    const int cbase = n0 + wc * 64;
    #pragma unroll
    for (int n = 0; n < 4; ++n) {
        const int col = cbase + n * 16 + lrow;
        const float bv = bias2[col];
        #pragma unroll
        for (int m = 0; m < 4; ++m) {
            const int row0 = rbase + m * 16;
            #pragma unroll
            for (int r = 0; r < 4; ++r) {
                C[(size_t)(row0 + r) * H_DIM + col] = acc[m][n][r] + bv;
            }
        }
    }
}

// ---------------- launcher ----------------
extern "C" void kernel_launch(void* const* d_in, const int* in_sizes, int n_in,
                              void* d_out, int out_size, void* d_ws, size_t ws_size,
                              hipStream_t stream) {
    const float* a      = (const float*)d_in[0];
    const float* v      = (const float*)d_in[1];
    const float* l      = (const float*)d_in[2];
    const float* qmask  = (const float*)d_in[3];
    // d_in[4] umask: unused by reference
    const float* mu_a   = (const float*)d_in[5];
    const float* mu_v   = (const float*)d_in[6];
    const float* mu_l   = (const float*)d_in[7];
    const float* shifta = (const float*)d_in[8];
    const float* shiftv = (const float*)d_in[9];
    const float* turna  = (const float*)d_in[10];
    const float* turnb  = (const float*)d_in[11];
    const float* W1     = (const float*)d_in[12];
    const float* b1     = (const float*)d_in[13];
    const float* W2     = (const float*)d_in[14];
    // d_in[15] b2: cancels in xr+xi
    float* out = (float*)d_out;

    char* ws = (char*)d_ws;
    unsigned short* Afeat = (unsigned short*)ws;                       // M*K_CAT bf16
    size_t offB  = (size_t)M_DIM * K_CAT * sizeof(unsigned short);     // 57.7 MB
    unsigned short* Bt = (unsigned short*)(ws + offB);                 // H*K_CAT bf16
    size_t offBias = offB + (size_t)H_DIM * K_CAT * sizeof(unsigned short);
    float* bias2 = (float*)(ws + offBias);
    size_t offTT = offBias + 4096;
    float4* TT = (float4*)(ws + offTT);                                // T*D float4

    prep_w_kernel<<<(H_DIM * K_CAT + 255) / 256, 256, 0, stream>>>(W1, b1, W2, Bt, bias2);
    prep_tt_kernel<<<(T_DIM * D_DIM + 255) / 256, 256, 0, stream>>>(turna, turnb, TT);
    feat_scan_kernel<<<B_DIM * 2, 256, 0, stream>>>(
        a, v, l, qmask, mu_a, mu_v, mu_l, shifta, shiftv, TT, (unsigned int*)Afeat);
    dim3 grid(M_DIM / BM, H_DIM / BN);
    gemm_kernel<<<grid, 256, 0, stream>>>(Afeat, Bt, bias2, out);
}

// Round 11
// 111.952 us; speedup vs baseline: 1.1345x; 1.1345x over previous
//
#include <hip/hip_runtime.h>

// ---------------- problem constants (fixed by reference) ----------------
#define T_DIM 110
#define B_DIM 256
#define D_DIM 512
#define H_DIM 512
#define K_CAT 1024              // K layout: interleaved (fr0,fi0,fr1,fi1,...)
#define M_DIM (T_DIM * B_DIM)   // 28160
#define BD    (B_DIM * D_DIM)   // 131072
#define EPSV 1e-9f

typedef float f32x4 __attribute__((ext_vector_type(4)));
typedef short bf16x8 __attribute__((ext_vector_type(8)));

static __device__ __forceinline__ unsigned short f2bf(float f) {
    unsigned u = __builtin_bit_cast(unsigned, f);
    u += 0x7fffu + ((u >> 16) & 1u);      // round-to-nearest-even
    return (unsigned short)(u >> 16);
}

// ---------------- kernel 1: weight prep, INTERLEAVED columns ------------------
// Bt[h][2j] = (W1+W2)[h][j] (multiplies fr_j); Bt[h][2j+1] = (W1-W2)[h][j]
// (multiplies fi_j). bias = 2*b1 (b2 cancels in xr+xi).
__global__ __launch_bounds__(256) void prep_w_kernel(
    const float* __restrict__ W1, const float* __restrict__ b1,
    const float* __restrict__ W2,
    unsigned short* __restrict__ Bt,   // [H][K_CAT] bf16
    float* __restrict__ bias2)         // [H]
{
    int i = blockIdx.x * 256 + threadIdx.x;
    if (i < H_DIM) bias2[i] = 2.0f * b1[i];
    if (i >= H_DIM * K_CAT) return;
    int h = i / K_CAT;
    int k = i % K_CAT;
    int j = k >> 1;
    float w = (k & 1) ? (W1[h * D_DIM + j] - W2[h * D_DIM + j])
                      : (W1[h * D_DIM + j] + W2[h * D_DIM + j]);
    Bt[i] = f2bf(w);
}

// ---------------- kernel 1b: turn-phase sincos table TT[t][d] = (ca,sa,cb,sb) --
__global__ __launch_bounds__(256) void prep_tt_kernel(
    const float* __restrict__ turna, const float* __restrict__ turnb,
    float4* __restrict__ TT)
{
    int i = blockIdx.x * 256 + threadIdx.x;
    if (i >= T_DIM * D_DIM) return;
    float s1, c1, s2, c2;
    __sincosf(turna[i], &s1, &c1);
    __sincosf(turnb[i], &s2, &c2);
    TT[i] = make_float4(c1, s1, c2, s2);
}

// ---------------- kernel 2: fused features + scan -> A[M][K_CAT] bf16 ----------
// (R10 version — measured ~46 us, keep verbatim.)
// Thread = one (b,d). Slot-static register ring depth 4, unroll 4: slot
// (t+4)&3 == t&3, so each iteration consumes its named set then reloads the
// SAME variables for t+4 (no rotation copies). sched_barrier(0x387) blocks
// ONLY VMEM from crossing iteration boundaries: pins prefetch loads at issue
// while letting VALU/DS flow across iterations. rsq(max(m2,1e-30)) replaces
// the IEEE divide (turn==0 stays exact: 0 * finite = 0).
__global__ __launch_bounds__(256) void feat_scan_kernel(
    const float* __restrict__ a, const float* __restrict__ v,
    const float* __restrict__ l, const float* __restrict__ qmask,
    const float* __restrict__ mu_a, const float* __restrict__ mu_v,
    const float* __restrict__ mu_l,
    const float* __restrict__ shifta, const float* __restrict__ shiftv,
    const float4* __restrict__ TT,
    unsigned int* __restrict__ A32)    // [M][K_CAT/2] dwords (fr|fi<<16)
{
    __shared__ float qm_s[T_DIM], mua_s[T_DIM], muv_s[T_DIM], mul_s[T_DIM];
    const int tx = threadIdx.x;
    const int b  = blockIdx.x >> 1;
    const int d  = ((blockIdx.x & 1) << 8) + tx;
    if (tx < T_DIM) {
        qm_s[tx]  = qmask[(size_t)(tx * B_DIM + b) * 2];
        mua_s[tx] = mu_a[tx];
        muv_s[tx] = mu_v[tx];
        mul_s[tx] = mu_l[tx];
    }
    const float sa = shifta[d];
    const float sv = shiftv[d];
    __syncthreads();

    const size_t gbase = (size_t)b * D_DIM + d;

    // ---- prologue: fill the 4 slots (t = 0..3) ----
    float  s0a = a[gbase],                 s0v = v[gbase],
           s0l = l[gbase];
    float4 s0t = TT[d];
    float  s1a = a[(size_t)1 * BD + gbase], s1v = v[(size_t)1 * BD + gbase],
           s1l = l[(size_t)1 * BD + gbase];
    float4 s1t = TT[1 * D_DIM + d];
    float  s2a = a[(size_t)2 * BD + gbase], s2v = v[(size_t)2 * BD + gbase],
           s2l = l[(size_t)2 * BD + gbase];
    float4 s2t = TT[2 * D_DIM + d];
    float  s3a = a[(size_t)3 * BD + gbase], s3v = v[(size_t)3 * BD + gbase],
           s3l = l[(size_t)3 * BD + gbase];
    float4 s3t = TT[3 * D_DIM + d];

    // pre-init (1,1): with gate=0 at t=0 the generic select reproduces the
    // reference's t=0 rule exactly.
    float pAr = 1.f, pAi = 1.f, pBr = 1.f, pBi = 1.f;

#define ITER(tt_, SA_, SV_, SL_, ST_)                                          \
    {                                                                          \
        const int t_ = (tt_);                                                  \
        const float qa = qm_s[t_], ma = mua_s[t_],                             \
                    mv = muv_s[t_], ml = mul_s[t_];                            \
        float sA, cA, sV, cV, sL, cL;                                          \
        __sincosf(SA_ + sa, &sA, &cA);                                         \
        __sincosf(SV_ + sv, &sV, &cV);                                         \
        __sincosf(SL_,      &sL, &cL);                                         \
        float fr = ml * cL + ma * cA + mv * cV;                                \
        float fi = ml * sL + ma * sA + mv * sV;                                \
        const bool isA = qa > 0.5f;                                            \
        const float cp = isA ? ST_.x : ST_.z;                                  \
        const float sp = isA ? ST_.y : ST_.w;                                  \
        const float pr = isA ? pAr : pBr;                                      \
        const float pi = isA ? pAi : pBi;                                      \
        const float tr = pr * cp - pi * sp;                                    \
        const float ti = pr * sp + pi * cp;                                    \
        const float gate = (t_ == 0) ? 0.0f : 1.0f;                            \
        const float m2 = fmaxf(tr * tr + ti * ti, 1e-30f);                     \
        const float inv = gate * __builtin_amdgcn_rsqf(m2);                    \
        fr += tr * inv;                                                        \
        fi += ti * inv;                                                        \
        pAr = isA ? fr : pAr;  pAi = isA ? fi : pAi;                           \
        pBr = isA ? pBr : fr;  pBi = isA ? pBi : fi;                           \
        A32[(size_t)(t_ * B_DIM + b) * (K_CAT / 2) + d] =                      \
            (unsigned)f2bf(fr) | ((unsigned)f2bf(fi) << 16);                   \
        /* reload SAME slot for t+4 (clamped; tail dups harmless) */           \
        const int tnx = (t_ + 4 < T_DIM) ? t_ + 4 : T_DIM - 1;                 \
        SA_ = a[(size_t)tnx * BD + gbase];                                     \
        SV_ = v[(size_t)tnx * BD + gbase];                                     \
        SL_ = l[(size_t)tnx * BD + gbase];                                     \
        ST_ = TT[(size_t)tnx * D_DIM + d];                                     \
        /* directional fence: VMEM may not cross; VALU/SALU/DS may */          \
        __builtin_amdgcn_sched_barrier(0x387);                                 \
    }

    // 27 groups cover t = 0..107; peel 108 (slot0), 109 (slot1).
    for (int tb = 0; tb < 108; tb += 4) {
        ITER(tb,     s0a, s0v, s0l, s0t)
        ITER(tb + 1, s1a, s1v, s1l, s1t)
        ITER(tb + 2, s2a, s2v, s2l, s2t)
        ITER(tb + 3, s3a, s3v, s3l, s3t)
    }
    ITER(108, s0a, s0v, s0l, s0t)
    ITER(109, s1a, s1v, s1l, s1t)
#undef ITER
}

// ---------------- kernel 3: bf16 MFMA GEMM  C = A @ Bt^T + bias ---------------
// REVERTED to the proven 1-phase m97 structure (R3-R9, ~38 us): 128x128 tile,
// BK=64, global_load_lds width-16 staging into LINEAR LDS [128][64] (32 KB
// total), 4 waves (2x2), 4x4 frags of 16x16x32, 2 barriers per K-step.
// R10 post-mortem: 2-phase dbuf (64 KB LDS) cut occupancy and regressed
// 38->77 us (m132 lesson) — do not re-attempt without an 8-phase schedule.
#define BM 128
#define BN 128
#define BK 64

__global__ __launch_bounds__(256) void gemm_kernel(
    const unsigned short* __restrict__ A,
    const unsigned short* __restrict__ Bt,
    const float* __restrict__ bias2,
    float* __restrict__ C)
{
    __shared__ __align__(16) unsigned short As[BM * BK];   // 16 KB, linear
    __shared__ __align__(16) unsigned short Bs[BN * BK];   // 16 KB, linear

    const int tid = threadIdx.x;
    const int wave = tid >> 6;
    const int lane = tid & 63;
    const int wr = wave >> 1;          // 0..1 (M dir)
    const int wc = wave & 1;           // 0..1 (N dir)
    const int m0 = blockIdx.x * BM;
    const int n0 = blockIdx.y * BN;
    const int lrow = lane & 15;
    const int lk8 = (lane >> 4) * 8;   // k-offset of this lane's 8 elements

    const int srow = wave * 32;        // first row this wave stages
    const int lrow8 = lane >> 3;       // row within 8-row group
    const int lchunk = lane & 7;       // 16B chunk within row

    f32x4 acc[4][4] = {};

    for (int k0 = 0; k0 < K_CAT; k0 += BK) {
        #pragma unroll
        for (int c = 0; c < 4; ++c) {
            const int row = srow + c * 8 + lrow8;
            {
                const unsigned short* gp = A + (size_t)(m0 + row) * K_CAT + k0 + lchunk * 8;
                unsigned short* lp = As + (srow + c * 8) * BK + lane * 8;
                __builtin_amdgcn_global_load_lds(
                    (const __attribute__((address_space(1))) unsigned int*)gp,
                    (__attribute__((address_space(3))) unsigned int*)lp,
                    16, 0, 0);
            }
            {
                const unsigned short* gp = Bt + (size_t)(n0 + row) * K_CAT + k0 + lchunk * 8;
                unsigned short* lp = Bs + (srow + c * 8) * BK + lane * 8;
                __builtin_amdgcn_global_load_lds(
                    (const __attribute__((address_space(1))) unsigned int*)gp,
                    (__attribute__((address_space(3))) unsigned int*)lp,
                    16, 0, 0);
            }
        }
        __syncthreads();

        bf16x8 af[4][2], bfv[4][2];
        #pragma unroll
        for (int m = 0; m < 4; ++m)
            #pragma unroll
            for (int kk = 0; kk < 2; ++kk)
                af[m][kk] = *reinterpret_cast<const bf16x8*>(
                    &As[(wr * 64 + m * 16 + lrow) * BK + kk * 32 + lk8]);
        #pragma unroll
        for (int n = 0; n < 4; ++n)
            #pragma unroll
            for (int kk = 0; kk < 2; ++kk)
                bfv[n][kk] = *reinterpret_cast<const bf16x8*>(
                    &Bs[(wc * 64 + n * 16 + lrow) * BK + kk * 32 + lk8]);

        #pragma unroll
        for (int kk = 0; kk < 2; ++kk)
            #pragma unroll
            for (int m = 0; m < 4; ++m)
                #pragma unroll
                for (int n = 0; n < 4; ++n)
                    acc[m][n] = __builtin_amdgcn_mfma_f32_16x16x32_bf16(
                        af[m][kk], bfv[n][kk], acc[m][n], 0, 0, 0);
        __syncthreads();
    }

    // -------- epilogue: C/D layout col=lane&15, row=(lane>>4)*4+r  (m89/m91)
    const int rbase = m0 + wr * 64 + (lane >> 4) * 4;
    const int cbase = n0 + wc * 64;
    #pragma unroll
    for (int n = 0; n < 4; ++n) {
        const int col = cbase + n * 16 + lrow;
        const float bv = bias2[col];
        #pragma unroll
        for (int m = 0; m < 4; ++m) {
            const int row0 = rbase + m * 16;
            #pragma unroll
            for (int r = 0; r < 4; ++r) {
                C[(size_t)(row0 + r) * H_DIM + col] = acc[m][n][r] + bv;
            }
        }
    }
}

// ---------------- launcher ----------------
extern "C" void kernel_launch(void* const* d_in, const int* in_sizes, int n_in,
                              void* d_out, int out_size, void* d_ws, size_t ws_size,
                              hipStream_t stream) {
    const float* a      = (const float*)d_in[0];
    const float* v      = (const float*)d_in[1];
    const float* l      = (const float*)d_in[2];
    const float* qmask  = (const float*)d_in[3];
    // d_in[4] umask: unused by reference
    const float* mu_a   = (const float*)d_in[5];
    const float* mu_v   = (const float*)d_in[6];
    const float* mu_l   = (const float*)d_in[7];
    const float* shifta = (const float*)d_in[8];
    const float* shiftv = (const float*)d_in[9];
    const float* turna  = (const float*)d_in[10];
    const float* turnb  = (const float*)d_in[11];
    const float* W1     = (const float*)d_in[12];
    const float* b1     = (const float*)d_in[13];
    const float* W2     = (const float*)d_in[14];
    // d_in[15] b2: cancels in xr+xi
    float* out = (float*)d_out;

    char* ws = (char*)d_ws;
    unsigned short* Afeat = (unsigned short*)ws;                       // M*K_CAT bf16
    size_t offB  = (size_t)M_DIM * K_CAT * sizeof(unsigned short);     // 57.7 MB
    unsigned short* Bt = (unsigned short*)(ws + offB);                 // H*K_CAT bf16
    size_t offBias = offB + (size_t)H_DIM * K_CAT * sizeof(unsigned short);
    float* bias2 = (float*)(ws + offBias);
    size_t offTT = offBias + 4096;
    float4* TT = (float4*)(ws + offTT);                                // T*D float4

    prep_w_kernel<<<(H_DIM * K_CAT + 255) / 256, 256, 0, stream>>>(W1, b1, W2, Bt, bias2);
    prep_tt_kernel<<<(T_DIM * D_DIM + 255) / 256, 256, 0, stream>>>(turna, turnb, TT);
    feat_scan_kernel<<<B_DIM * 2, 256, 0, stream>>>(
        a, v, l, qmask, mu_a, mu_v, mu_l, shifta, shiftv, TT, (unsigned int*)Afeat);
    dim3 grid(M_DIM / BM, H_DIM / BN);
    gemm_kernel<<<grid, 256, 0, stream>>>(Afeat, Bt, bias2, out);
}